// Round 10
// baseline (235.851 us; speedup 1.0000x reference)
//
#include <hip/hip_runtime.h>
#include <hip/hip_bf16.h>
#include <stdint.h>

// CausalSelfAttention  B=2 L=4096 D=768 H=12 Dh=64
// Dual-dtype inputs (fp32 reference or bf16-lowered), detected on device.
// Internals bf16 MFMA. ws: flag(64B) | q,k planes [bh][l][64] | vT plane
// [bh][d][L] | y/xbf overlay [8192][768] | WqkvT [2304][768] | WoT [768][768]
// R17 = R16 consolidation:
//  - qkv256_k now handles ALL of N=2304 (grid (64,9), 512 thr): q/k epilogue
//    for n0<1536 (verbatim R16), NEW v transpose epilogue for n0>=1536
//    (old qkv128 formulas re-indexed: 4 rounds x 64 cols over 8 waves, Ts
//    overlaid on dead staging LDS). One launch instead of two serialized
//    (qkv128-v ran alone at 1.5 blocks/CU = tail).
//  - out64_k upgraded to the same T3 2-phase dbuf (stage t+1 before compute,
//    ONE sync/K-tile, was 2 drain barriers). LDS 24KB, 3 blocks/CU.
//  - attn/prep/detect untouched (control: expect identical counters).
#define BB 2
#define LL 4096
#define DD 768
#define HH 12
#define DH 64
#define MM (BB * LL)
#define NQKV (3 * DD)
#define KK 768
#define PLANE ((size_t)BB * HH * LL * DH)
#define SQSCALE 0.1803368801111204f   // 0.125 * log2(e)

typedef __attribute__((ext_vector_type(8))) short bf16x8;
typedef __attribute__((ext_vector_type(4))) float f32x4;

__device__ __forceinline__ float bf2f(uint16_t u) {
  union { uint32_t u; float f; } c; c.u = ((uint32_t)u) << 16; return c.f;
}
__device__ __forceinline__ uint16_t f2bf(float f) {
  union { float f; uint32_t u; } c; c.f = f;
  return (uint16_t)((c.u + 0x7FFFu + ((c.u >> 16) & 1u)) >> 16);
}
// packed 2xf32 -> 2xbf16 (v_cvt_pk_bf16_f32); a low 16, b high 16
__device__ __forceinline__ uint32_t cvt2(float a, float b) {
  __hip_bfloat162 h = __float22bfloat162_rn(make_float2(a, b));
  union { __hip_bfloat162 h; uint32_t u; } c; c.h = h; return c.u;
}
// raw 2^x, single v_exp_f32 (scores bounded; tol 3.9e-3 >> 1ulp)
#if __has_builtin(__builtin_amdgcn_exp2f)
__device__ __forceinline__ float fexp2(float x) { return __builtin_amdgcn_exp2f(x); }
#else
__device__ __forceinline__ float fexp2(float x) {
  float r;
  asm volatile("v_exp_f32 %0, %1\ns_nop 0" : "=v"(r) : "v"(x));  // trans hazard
  return r;
}
#endif

union H8 { uint16_t h[8]; uint32_t w[4]; uint4 v; };
union B8 { uint2 d[2]; bf16x8 v; };

template <bool F32>
__device__ __forceinline__ H8 load8(const void* p, size_t idx) {
  H8 r;
  if (F32) {
    const float* f = (const float*)p + idx;
    float4 a = *(const float4*)f;
    float4 b = *(const float4*)(f + 4);
    r.w[0] = cvt2(a.x, a.y); r.w[1] = cvt2(a.z, a.w);
    r.w[2] = cvt2(b.x, b.y); r.w[3] = cvt2(b.z, b.w);
  } else {
    r.v = *(const uint4*)((const uint16_t*)p + idx);
  }
  return r;
}

// async global->LDS, 16B per lane; lds ptr wave-uniform
__device__ __forceinline__ void g2l16(const uint16_t* g, uint16_t* l) {
  __builtin_amdgcn_global_load_lds((const __attribute__((address_space(1))) void*)g,
                                   (__attribute__((address_space(3))) void*)l,
                                   16, 0, 0);
}

// ---------------- dtype detection ------------------------------------------
__global__ void detect_k(const uint16_t* __restrict__ x, int* __restrict__ flag) {
  __shared__ int cnt;
  if (threadIdx.x == 0) cnt = 0;
  __syncthreads();
  int c = 0;
  for (int i = threadIdx.x; i < 4096; i += 256) {
    int e = (x[i] >> 7) & 0xFF;
    if (e == 0xFF || e > 133 || e < 100) c++;
  }
  atomicAdd(&cnt, c);
  __syncthreads();
  if (threadIdx.x == 0) *flag = (cnt > 512) ? 1 : 0;
}

// ---------------- merged prep: x->bf16, WqkvT, WoT -------------------------
__global__ __launch_bounds__(256) void prep_k(const void* __restrict__ x,
                                              uint16_t* __restrict__ xbf,
                                              const void* __restrict__ Wqkv,
                                              uint16_t* __restrict__ wqkvT,
                                              const void* __restrict__ Wo,
                                              uint16_t* __restrict__ woT,
                                              const int* __restrict__ flag) {
  __shared__ uint16_t Ts[64][65];
  const int fl = *flag;
  const int id = blockIdx.x;
  const int tid = threadIdx.x;
  if (id < 768) {
    size_t base = (size_t)id * 1024 + tid;
#pragma unroll
    for (int j = 0; j < 4; ++j) {
      size_t i = base + j * 256;
      H8 v = fl ? load8<true>(x, i * 8) : load8<false>(x, i * 8);
      *(uint4*)(xbf + i * 8) = v.v;
    }
    return;
  }
  const void* W;
  uint16_t* WT;
  int N, widx;
  if (id < 1200) { W = Wqkv; WT = wqkvT; N = NQKV; widx = id - 768; }
  else           { W = Wo;   WT = woT;   N = DD;   widx = id - 1200; }
  const int nb = N / 64;
  const int n0 = (widx % nb) * 64, k0 = (widx / nb) * 64;
#pragma unroll
  for (int j = 0; j < 16; ++j) {
    int idx = tid + j * 256;
    int r = idx >> 6, c = idx & 63;
    size_t gi = (size_t)(k0 + r) * N + n0 + c;
    float v = fl ? ((const float*)W)[gi] : bf2f(((const uint16_t*)W)[gi]);
    Ts[c][r] = f2bf(v);
  }
  __syncthreads();
#pragma unroll
  for (int j = 0; j < 16; ++j) {
    int idx = tid + j * 256;
    int n = idx >> 6, k = idx & 63;
    WT[(size_t)(n0 + n) * KK + k0 + k] = Ts[n][k];
  }
}

// ---------------- kernel: QKV projection, ALL sections (128m x 256n) -------
// 512 thr = 8 waves (2m x 4n), wave tile 64x64 (acc[4][4]). BK=32, depth-2
// LDS dbuf (48KB): stage tile t+1 BEFORE compute of t, ONE sync per tile.
// Epilogue: q/k direct-store (n0<1536) or v transpose->vT plane (n0>=1536).
__global__ __launch_bounds__(512, 4) void qkv256_k(const uint16_t* __restrict__ X,
                                                   const uint16_t* __restrict__ WT,
                                                   const void* __restrict__ bias,
                                                   uint16_t* __restrict__ planes,
                                                   const int* __restrict__ flag) {
  __shared__ __align__(16) uint16_t smem[24576];   // 48KB: A0|A1|B0|B1
  const int fl = *flag;
  const int m0 = blockIdx.x * 128, n0 = blockIdx.y * 256;
  const int tid = threadIdx.x, lane = tid & 63, wv = tid >> 6;
  const int quad = lane >> 4, c16 = lane & 15;
  const int wm = wv >> 2, wn = wv & 3;
  const int srow = lane >> 2, schunk = lane & 3;
  const int rsw = (c16 >> 1) & 3;

  // staging rows: A: wave wv does rows wv*16+srow (1 instr);
  //               B: rows wv*32 + i*16 + srow (2 instr)
  const int ra = wv * 16 + srow;
  const int rb0 = wv * 32 + srow;
  const int rb1 = wv * 32 + 16 + srow;
  const int ga = schunk ^ ((ra >> 1) & 3);
  const int gb0 = schunk ^ ((rb0 >> 1) & 3);
  const int gb1 = schunk ^ ((rb1 >> 1) & 3);
  const uint16_t* gpa = X + (size_t)(m0 + ra) * KK + ga * 8;
  const uint16_t* gpb0 = WT + (size_t)(n0 + rb0) * KK + gb0 * 8;
  const uint16_t* gpb1 = WT + (size_t)(n0 + rb1) * KK + gb1 * 8;
  const int la = (wv * 16) * 32;
  const int lb0 = (wv * 32) * 32;
  const int lb1 = (wv * 32 + 16) * 32;

  f32x4 acc[4][4];
#pragma unroll
  for (int i = 0; i < 4; ++i)
#pragma unroll
    for (int f = 0; f < 4; ++f) acc[i][f] = (f32x4){0.f, 0.f, 0.f, 0.f};

  // prologue: stage tile 0 into buf 0 (A at 0, B at 8192 elem)
  g2l16(gpa, smem + la);
  g2l16(gpb0, smem + 8192 + lb0);
  g2l16(gpb1, smem + 8192 + lb1);
  __syncthreads();

  const int NT = KK / 32;
  for (int t = 0; t < NT; ++t) {
    const int aoff = (t & 1) ? 4096 : 0;          // current A buf
    const int boff = (t & 1) ? 16384 : 8192;      // current B buf
    if (t + 1 < NT) {                  // stage t+1 first (latency hides
      const int koff = (t + 1) * 32;   //  under this tile's compute)
      g2l16(gpa + koff, smem + (4096 - aoff) + la);
      g2l16(gpb0 + koff, smem + (24576 - boff) + lb0);
      g2l16(gpb1 + koff, smem + (24576 - boff) + lb1);
    }
    bf16x8 a[4], b[4];
#pragma unroll
    for (int i = 0; i < 4; ++i)
      a[i] = *(const bf16x8*)(smem + aoff + (wm * 64 + i * 16 + c16) * 32 + ((quad ^ rsw) * 8));
#pragma unroll
    for (int f = 0; f < 4; ++f)
      b[f] = *(const bf16x8*)(smem + boff + (wn * 64 + f * 16 + c16) * 32 + ((quad ^ rsw) * 8));
    __builtin_amdgcn_s_setprio(1);
#pragma unroll
    for (int i = 0; i < 4; ++i)
#pragma unroll
      for (int f = 0; f < 4; ++f)
        acc[i][f] = __builtin_amdgcn_mfma_f32_16x16x32_bf16(a[i], b[f], acc[i][f], 0, 0, 0);
    __builtin_amdgcn_s_setprio(0);
    __syncthreads();   // drains t+1 stages (issued a full tile ago) + publish
  }

  if (n0 < 2 * DD) {
    // ---- q/k epilogue (no tile straddles 768 boundary: 256 | 768) ----
    const int which = (n0 >= DD) ? 1 : 0;
    uint16_t* dst = planes + (size_t)which * PLANE;
    const float sc = (which == 0) ? SQSCALE : 1.0f;
#pragma unroll
    for (int f = 0; f < 4; ++f) {
      int n = n0 + wn * 64 + f * 16 + c16;
      float bv = fl ? ((const float*)bias)[n] : bf2f(((const uint16_t*)bias)[n]);
      int rem = n - which * DD;
      int hh = rem >> 6, dd = rem & 63;
#pragma unroll
      for (int i = 0; i < 4; ++i) {
        uint32_t pa = cvt2((acc[i][f][0] + bv) * sc, (acc[i][f][1] + bv) * sc);
        uint32_t pb = cvt2((acc[i][f][2] + bv) * sc, (acc[i][f][3] + bv) * sc);
        int m = m0 + wm * 64 + i * 16 + quad * 4;
        int b2 = m >> 12, l = m & (LL - 1);
        uint16_t* base = dst + ((size_t)(b2 * HH + hh) * LL + l) * DH + dd;
        base[0 * DH] = (uint16_t)pa;
        base[1 * DH] = (uint16_t)(pa >> 16);
        base[2 * DH] = (uint16_t)pb;
        base[3 * DH] = (uint16_t)(pb >> 16);
      }
    }
  } else {
    // ---- v transpose epilogue -> vT plane [d][L], 4 rounds x 64 cols ----
    uint16_t (*Ts)[136] = reinterpret_cast<uint16_t(*)[136]>(smem);  // 17KB overlay
    uint16_t* vtp = planes + 2 * PLANE;
    const int l0 = m0 & (LL - 1), bb = m0 >> 12;
    for (int g64 = 0; g64 < 4; ++g64) {
      if (wn == g64) {
#pragma unroll
        for (int f = 0; f < 4; ++f) {
          int n = n0 + g64 * 64 + f * 16 + c16;
          float bv = fl ? ((const float*)bias)[n] : bf2f(((const uint16_t*)bias)[n]);
#pragma unroll
          for (int i = 0; i < 4; ++i) {
            uint32_t pa = cvt2(acc[i][f][0] + bv, acc[i][f][1] + bv);
            uint32_t pb = cvt2(acc[i][f][2] + bv, acc[i][f][3] + bv);
            *(uint2*)(&Ts[f * 16 + c16][wm * 64 + i * 16 + quad * 4]) = make_uint2(pa, pb);
          }
        }
      }
      __syncthreads();
#pragma unroll
      for (int j = 0; j < 2; ++j) {
        int idx = tid + j * 512;
        int nl = idx >> 4, ch = idx & 15;
        int rem = n0 + g64 * 64 + nl - 2 * DD;
        int hh = rem >> 6, dd = rem & 63;
        uint4 val = *(const uint4*)(&Ts[nl][ch * 8]);
        *(uint4*)(vtp + ((size_t)(bb * HH + hh) * DH + dd) * LL + l0 + ch * 8) = val;
      }
      __syncthreads();
    }
  }
}

// ---------------- kernel: flash attention (KVBLK=128, key-split waves) -----
__global__ __launch_bounds__(256, 3) void attn_k(const uint16_t* __restrict__ planes,
                                                 uint16_t* __restrict__ y) {
  __shared__ __align__(16) uint16_t Ks[2][128 * 64];  // 32KB dbuf, g2l16 direct
  __shared__ __align__(16) uint16_t Vt[64 * 128];     // 16KB, pi+G swizzled
  // XCD-aware 1D grid: all 32 blocks of a bh share id%8 -> same XCD L2.
  const int id = blockIdx.x;           // 0..767
  const int p = id / 24;               // 0..31 -> q tiles {63-p, p}
  const int bh = id % 24;              // 0..23 (id%8 = bh%8 = XCD)
  const uint16_t* qb = planes + (size_t)bh * LL * DH;
  const uint16_t* kb = qb + PLANE;
  const uint16_t* vtb = planes + 2 * PLANE + (size_t)bh * DH * LL;  // [d][L]
  const int tid = threadIdx.x, lane = tid & 63, wv = tid >> 6;
  const int quad = lane >> 4, c16 = lane & 15;
  const int swf = c16 & 7;
  const int qsub = wv & 1;             // q 32-group within the 64-q tile
  const int kg = wv >> 1;              // key 64-half within the 128-key tile
  const int b = bh / HH, hh = bh - b * HH;

  // K staging via g2l16: linear LDS dest, swizzle folded into GLOBAL src.
  int koff[4];
  {
    int cp = lane & 7;
#pragma unroll
    for (int i = 0; i < 4; ++i) {
      int row = wv * 32 + i * 8 + (lane >> 3);
      koff[i] = row * 64 + ((cp ^ (row & 7)) * 8);
    }
  }
  const int kdst = wv * 32 * 64;   // elems; + i*512 per instruction

  // V staging lane map (granule-bijective per quarter-wave, R14-verified)
  const int vkg = ((tid >> 2) & 1) | ((tid & 1) << 1);
  const int vdr = ((tid >> 1) & 1) | (((tid >> 4) & 1) << 1) |
                  (((tid >> 3) & 1) << 2) | ((tid >> 5) << 3);
  const int swd = vdr & 7;
  int vwoff[4][2];
#pragma unroll
  for (int j = 0; j < 4; ++j) {
#pragma unroll
    for (int h = 0; h < 2; ++h) {
      int ks = (vkg + 4 * j) * 8 + 4 * h;          // global 4-key group base
      int G = ks >> 6, ks6 = ks & 63;
      int ch = ((ks6 & 32) >> 3) + ((ks6 >> 2) & 3);
      int f4 = ((ks6 >> 4) & 1) * 4;
      vwoff[j][h] = vdr * 128 + G * 64 + ((ch ^ swd ^ (G << 2)) * 8) + f4;
    }
  }

  B8 ones;   // all-ones bf16 B fragment for l-sum MFMA
  ones.d[0] = make_uint2(0x3F803F80u, 0x3F803F80u);
  ones.d[1] = make_uint2(0x3F803F80u, 0x3F803F80u);

  float* osm = (float*)(&Ks[0][0]);    // epilogue o/l staging (20KB < 32KB)

  for (int pass = 0; pass < 2; ++pass) {
    const int qi = pass ? p : 63 - p;
    const int nt = (qi + 2) >> 1;        // 128-key tiles; pair sums to 33
    const int q0 = qi * 64;
    bf16x8 qf[2][2];
#pragma unroll
    for (int s = 0; s < 2; ++s) {
      size_t qoff = (size_t)(q0 + qsub * 32 + s * 16 + c16) * DH;
      qf[s][0] = *(const bf16x8*)(qb + qoff + quad * 8);
      qf[s][1] = *(const bf16x8*)(qb + qoff + 32 + quad * 8);
    }

    f32x4 o[2][4], la[2];
#pragma unroll
    for (int s = 0; s < 2; ++s) {
      la[s] = (f32x4){0.f, 0.f, 0.f, 0.f};
#pragma unroll
      for (int g = 0; g < 4; ++g) o[s][g] = (f32x4){0.f, 0.f, 0.f, 0.f};
    }

    // prologue: stage tile 0 (K->LDS async, V->regs)
    const uint16_t* ksrc = kb;
    const uint16_t* vp = vtb + (size_t)vdr * LL + vkg * 8;
    uint4 vrg[4];
#pragma unroll
    for (int i = 0; i < 4; ++i) g2l16(ksrc + koff[i], Ks[0] + kdst + i * 512);
#pragma unroll
    for (int j = 0; j < 4; ++j) vrg[j] = *(const uint4*)(vp + j * 32);
    ksrc += 128 * DH; vp += 128;

    for (int t = 0; t < nt; ++t) {
      const uint16_t* kd = Ks[t & 1];
      uint16_t* knx = Ks[(t + 1) & 1];
      __syncthreads();   // A: prev readers done; drains K g2l16 + vrg loads
#pragma unroll
      for (int j = 0; j < 4; ++j) {
        *(uint2*)(Vt + vwoff[j][0]) = make_uint2(vrg[j].x, vrg[j].y);
        *(uint2*)(Vt + vwoff[j][1]) = make_uint2(vrg[j].z, vrg[j].w);
      }
      __syncthreads();   // B: Vt + Ks[t&1] visible
      if (t + 1 < nt) {  // prefetch t+1: latency hides under compute below
#pragma unroll
        for (int i = 0; i < 4; ++i) g2l16(ksrc + koff[i], knx + kdst + i * 512);
#pragma unroll
        for (int j = 0; j < 4; ++j) vrg[j] = *(const uint4*)(vp + j * 32);
        ksrc += 128 * DH; vp += 128;
      }

      // K fragments for this wave's 64-key half, reused across both q-subtiles
      bf16x8 kfr[4][2];
#pragma unroll
      for (int f = 0; f < 4; ++f) {
        const uint16_t* krow = kd + (kg * 64 + f * 16 + c16) * 64;
        kfr[f][0] = *(const bf16x8*)(krow + ((quad ^ swf) * 8));
        kfr[f][1] = *(const bf16x8*)(krow + (((quad + 4) ^ swf) * 8));
      }
      B8 pk[2][2];
#pragma unroll
      for (int s = 0; s < 2; ++s) {
        f32x4 sv[4];
        __builtin_amdgcn_s_setprio(1);
#pragma unroll
        for (int f = 0; f < 4; ++f) {
          f32x4 z = {0.f, 0.f, 0.f, 0.f};
          z = __builtin_amdgcn_mfma_f32_16x16x32_bf16(kfr[f][0], qf[s][0], z, 0, 0, 0);
          z = __builtin_amdgcn_mfma_f32_16x16x32_bf16(kfr[f][1], qf[s][1], z, 0, 0, 0);
          sv[f] = z;
        }
        __builtin_amdgcn_s_setprio(0);
        const int qg = q0 + qsub * 32 + s * 16 + c16;
        if (t == nt - 1) {
#pragma unroll
          for (int f = 0; f < 4; ++f) {
            int key0 = t * 128 + kg * 64 + f * 16 + quad * 4;
#pragma unroll
            for (int r = 0; r < 4; ++r) {
              float pv = fexp2(sv[f][r]);
              sv[f][r] = (key0 + r <= qg) ? pv : 0.f;
            }
          }
        } else {
#pragma unroll
          for (int f = 0; f < 4; ++f)
#pragma unroll
            for (int r = 0; r < 4; ++r) sv[f][r] = fexp2(sv[f][r]);
        }
        pk[s][0].d[0] = make_uint2(cvt2(sv[0][0], sv[0][1]), cvt2(sv[0][2], sv[0][3]));
        pk[s][0].d[1] = make_uint2(cvt2(sv[1][0], sv[1][1]), cvt2(sv[1][2], sv[1][3]));
        pk[s][1].d[0] = make_uint2(cvt2(sv[2][0], sv[2][1]), cvt2(sv[2][2], sv[2][3]));
        pk[s][1].d[1] = make_uint2(cvt2(sv[3][0], sv[3][1]), cvt2(sv[3][2], sv[3][3]));
      }
      // l-sum via ones-B MFMA + PV over this wave's key half
      __builtin_amdgcn_s_setprio(1);
#pragma unroll
      for (int s = 0; s < 2; ++s)
#pragma unroll
        for (int j = 0; j < 2; ++j)
          la[s] = __builtin_amdgcn_mfma_f32_16x16x32_bf16(pk[s][j].v, ones.v, la[s], 0, 0, 0);
#pragma unroll
      for (int g = 0; g < 4; ++g) {
        const uint16_t* vrow = Vt + (g * 16 + c16) * 128 + kg * 64;
#pragma unroll
        for (int j = 0; j < 2; ++j) {
          int chunk = (quad + 4 * j) ^ swf ^ (kg << 2);
          bf16x8 vv = *(const bf16x8*)(vrow + chunk * 8);
          o[0][g] = __builtin_amdgcn_mfma_f32_16x16x32_bf16(pk[0][j].v, vv, o[0][g], 0, 0, 0);
          o[1][g] = __builtin_amdgcn_mfma_f32_16x16x32_bf16(pk[1][j].v, vv, o[1][g], 0, 0, 0);
        }
      }
      __builtin_amdgcn_s_setprio(0);
    }

    // cross-wave (key-half) reduction: kg=1 stages partials, kg=0 finishes
    __syncthreads();   // all LDS reads of last tile done
    if (kg == 1) {
#pragma unroll
      for (int s = 0; s < 2; ++s) {
#pragma unroll
        for (int g = 0; g < 4; ++g)
          *(f32x4*)(osm + ((qsub * 8 + s * 4 + g) * 64 + lane) * 4) = o[s][g];
        *(f32x4*)(osm + 4096 + ((qsub * 2 + s) * 64 + lane) * 4) = la[s];
      }
    }
    __syncthreads();
    if (kg == 0) {
#pragma unroll
      for (int s = 0; s < 2; ++s) {
        f32x4 lp = *(const f32x4*)(osm + 4096 + ((qsub * 2 + s) * 64 + lane) * 4);
        float inv[4];
#pragma unroll
        for (int r = 0; r < 4; ++r) inv[r] = 1.f / (la[s][r] + lp[r]);
        int l = q0 + qsub * 32 + s * 16 + quad * 4;
#pragma unroll
        for (int g = 0; g < 4; ++g) {
          f32x4 op = *(const f32x4*)(osm + ((qsub * 8 + s * 4 + g) * 64 + lane) * 4);
          float v0 = (o[s][g][0] + op[0]) * inv[0];
          float v1 = (o[s][g][1] + op[1]) * inv[1];
          float v2 = (o[s][g][2] + op[2]) * inv[2];
          float v3 = (o[s][g][3] + op[3]) * inv[3];
          uint32_t pa = cvt2(v0, v1);
          uint32_t pb = cvt2(v2, v3);
          uint16_t* base = y + ((size_t)(b * LL + l)) * DD + hh * DH + g * 16 + c16;
          base[0 * DD] = (uint16_t)pa;
          base[1 * DD] = (uint16_t)(pa >> 16);
          base[2 * DD] = (uint16_t)pb;
          base[3 * DD] = (uint16_t)(pb >> 16);
        }
      }
    }
    __syncthreads();   // pass boundary: next pass's g2l16 must not race reads
  }
}

// ---------------- kernel: output projection (128m x 64n, 2-phase dbuf) -----
__global__ __launch_bounds__(256) void out64_k(const uint16_t* __restrict__ Y,
                                               const uint16_t* __restrict__ WT,
                                               const void* __restrict__ bias,
                                               void* __restrict__ out,
                                               const int* __restrict__ flag) {
  __shared__ __align__(16) uint16_t smem[12288];   // 24KB: A0|A1|B0|B1
  const int fl = *flag;
  const int m0 = blockIdx.x * 128, n0 = blockIdx.y * 64;
  const int tid = threadIdx.x, lane = tid & 63, w = tid >> 6;
  const int quad = lane >> 4, c16 = lane & 15;
  const int srow = lane >> 2, schunk = lane & 3;
  const int rsw = (c16 >> 1) & 3;

  // staging rows: A: wave w rows w*32+i*16+srow (2 instr); B: w*16+srow (1)
  const int ra0 = w * 32 + srow;
  const int ra1 = w * 32 + 16 + srow;
  const int rb = w * 16 + srow;
  const int gA0 = schunk ^ ((ra0 >> 1) & 3);
  const int gA1 = schunk ^ ((ra1 >> 1) & 3);
  const int gB = schunk ^ ((rb >> 1) & 3);
  const uint16_t* gpa0 = Y + (size_t)(m0 + ra0) * KK + gA0 * 8;
  const uint16_t* gpa1 = Y + (size_t)(m0 + ra1) * KK + gA1 * 8;
  const uint16_t* gpb = WT + (size_t)(n0 + rb) * KK + gB * 8;
  const int la0 = (w * 32) * 32;
  const int la1 = (w * 32 + 16) * 32;
  const int lb = (w * 16) * 32;

  f32x4 acc[2][4];
#pragma unroll
  for (int i = 0; i < 2; ++i)
#pragma unroll
    for (int f = 0; f < 4; ++f) acc[i][f] = (f32x4){0.f, 0.f, 0.f, 0.f};

  // prologue: stage tile 0 (A at 0, B at 8192 elem)
  g2l16(gpa0, smem + la0);
  g2l16(gpa1, smem + la1);
  g2l16(gpb, smem + 8192 + lb);
  __syncthreads();

  const int NT = KK / 32;
  for (int t = 0; t < NT; ++t) {
    const int aoff = (t & 1) ? 4096 : 0;
    const int boff = (t & 1) ? 10240 : 8192;
    if (t + 1 < NT) {
      const int koff = (t + 1) * 32;
      g2l16(gpa0 + koff, smem + (4096 - aoff) + la0);
      g2l16(gpa1 + koff, smem + (4096 - aoff) + la1);
      g2l16(gpb + koff, smem + (18432 - boff) + lb);
    }
    bf16x8 a[2], bfr[4];
#pragma unroll
    for (int i = 0; i < 2; ++i)
      a[i] = *(const bf16x8*)(smem + aoff + (w * 32 + i * 16 + c16) * 32 + ((quad ^ rsw) * 8));
#pragma unroll
    for (int f = 0; f < 4; ++f)
      bfr[f] = *(const bf16x8*)(smem + boff + (f * 16 + c16) * 32 + ((quad ^ rsw) * 8));
    __builtin_amdgcn_s_setprio(1);
#pragma unroll
    for (int i = 0; i < 2; ++i)
#pragma unroll
      for (int f = 0; f < 4; ++f)
        acc[i][f] = __builtin_amdgcn_mfma_f32_16x16x32_bf16(a[i], bfr[f], acc[i][f], 0, 0, 0);
    __builtin_amdgcn_s_setprio(0);
    __syncthreads();
  }
#pragma unroll
  for (int f = 0; f < 4; ++f) {
    int n = n0 + f * 16 + c16;
    float bv = fl ? ((const float*)bias)[n] : bf2f(((const uint16_t*)bias)[n]);
#pragma unroll
    for (int i = 0; i < 2; ++i) {
      int m = m0 + w * 32 + i * 16 + quad * 4;
      if (fl) {
        float* base = (float*)out + (size_t)m * DD + n;
#pragma unroll
        for (int r = 0; r < 4; ++r) base[r * DD] = acc[i][f][r] + bv;
      } else {
        uint32_t pa = cvt2(acc[i][f][0] + bv, acc[i][f][1] + bv);
        uint32_t pb = cvt2(acc[i][f][2] + bv, acc[i][f][3] + bv);
        uint16_t* base = (uint16_t*)out + (size_t)m * DD + n;
        base[0 * DD] = (uint16_t)pa;
        base[1 * DD] = (uint16_t)(pa >> 16);
        base[2 * DD] = (uint16_t)pb;
        base[3 * DD] = (uint16_t)(pb >> 16);
      }
    }
  }
}

extern "C" void kernel_launch(void* const* d_in, const int* in_sizes, int n_in,
                              void* d_out, int out_size, void* d_ws, size_t ws_size,
                              hipStream_t stream) {
  const void* x    = d_in[0];
  const void* Wqkv = d_in[1];
  const void* bqkv = d_in[2];
  const void* Wo   = d_in[3];
  const void* bo   = d_in[4];
  int* flagp = (int*)d_ws;
  uint16_t* planes = (uint16_t*)((char*)d_ws + 64);
  uint16_t* y_ws   = planes + 3 * PLANE;
  uint16_t* wqkvT  = y_ws + (size_t)MM * DD;
  uint16_t* woT    = wqkvT + (size_t)NQKV * KK;
  uint16_t* xbf    = y_ws;   // overlay: consumed before attn writes y

  detect_k<<<1, 256, 0, stream>>>((const uint16_t*)x, flagp);
  prep_k<<<1344, 256, 0, stream>>>(x, xbf, Wqkv, wqkvT, Wo, woT, flagp);
  qkv256_k<<<dim3(MM / 128, NQKV / 256), 512, 0, stream>>>(xbf, wqkvT, bqkv, planes, flagp);
  attn_k<<<dim3(768), 256, 0, stream>>>(planes, y_ws);
  out64_k<<<dim3(MM / 128, DD / 64), 256, 0, stream>>>(y_ws, woT, bo, d_out, flagp);
}